// Round 1
// baseline (265.972 us; speedup 1.0000x reference)
//
#include <hip/hip_runtime.h>
#include <hip/hip_bf16.h>

#define D 32
#define FACTOR (-1.0f / 128.0f)   // -1/(2*BANDWIDTH^2), BANDWIDTH=8

// ---------------------------------------------------------------------------
// Kernel 0: y2[m] = sum_d ref[m][d]^2
// ---------------------------------------------------------------------------
__global__ __launch_bounds__(256) void msk_y2(const float* __restrict__ ref,
                                              float* __restrict__ y2, int M) {
    int m = blockIdx.x * blockDim.x + threadIdx.x;
    if (m >= M) return;
    const float* y = ref + (size_t)m * D;
    float s0 = 0.f, s1 = 0.f, s2 = 0.f, s3 = 0.f;
#pragma unroll
    for (int d = 0; d < D; d += 4) {
        float4 v = *reinterpret_cast<const float4*>(y + d);
        s0 = fmaf(v.x, v.x, s0);
        s1 = fmaf(v.y, v.y, s1);
        s2 = fmaf(v.z, v.z, s2);
        s3 = fmaf(v.w, v.w, s3);
    }
    y2[m] = (s0 + s1) + (s2 + s3);
}

// ---------------------------------------------------------------------------
// Kernel 1: per-(point, m-chunk) partial sums.
//   grid.x * 256 threads = N points (one point per thread)
//   grid.y = S chunks over m; each chunk has `chunk` reference rows.
//   partial layout: part[(s*N + n)*33 + k], k<32 = nom[k], k==32 = den
// ---------------------------------------------------------------------------
__global__ __launch_bounds__(256) void msk_partial(const float* __restrict__ pts,
                                                   const float* __restrict__ ref,
                                                   const float* __restrict__ y2buf,
                                                   float* __restrict__ part,
                                                   int N, int chunk) {
    const int n  = blockIdx.x * blockDim.x + threadIdx.x;   // point index
    const int m0 = blockIdx.y * chunk;                      // chunk start (uniform)

    // Load this thread's point into registers.
    float x[D];
#pragma unroll
    for (int d = 0; d < D; d += 4) {
        float4 v = *reinterpret_cast<const float4*>(pts + (size_t)n * D + d);
        x[d + 0] = v.x; x[d + 1] = v.y; x[d + 2] = v.z; x[d + 3] = v.w;
    }
    float x2 = 0.f;
#pragma unroll
    for (int d = 0; d < D; ++d) x2 = fmaf(x[d], x[d], x2);

    float nom[D];
#pragma unroll
    for (int d = 0; d < D; ++d) nom[d] = 0.f;
    float den = 0.f;

    for (int mt = 0; mt < chunk; ++mt) {
        const int m = m0 + mt;                              // uniform across block
        const float* y = ref + (size_t)m * D;               // -> scalar loads
        float yv[D];
#pragma unroll
        for (int d = 0; d < D; d += 4) {
            float4 v = *reinterpret_cast<const float4*>(y + d);
            yv[d + 0] = v.x; yv[d + 1] = v.y; yv[d + 2] = v.z; yv[d + 3] = v.w;
        }
        // dot(x, y) with 4 independent accumulator chains
        float d0 = 0.f, d1 = 0.f, d2 = 0.f, d3 = 0.f;
#pragma unroll
        for (int d = 0; d < D; d += 4) {
            d0 = fmaf(x[d + 0], yv[d + 0], d0);
            d1 = fmaf(x[d + 1], yv[d + 1], d1);
            d2 = fmaf(x[d + 2], yv[d + 2], d2);
            d3 = fmaf(x[d + 3], yv[d + 3], d3);
        }
        const float dot = (d0 + d1) + (d2 + d3);
        const float s   = x2 + y2buf[m] - 2.0f * dot;
        const float k   = __expf(s * FACTOR);
        den += k;
#pragma unroll
        for (int d = 0; d < D; ++d) nom[d] = fmaf(k, yv[d], nom[d]);
    }

    float* p = part + ((size_t)blockIdx.y * N + n) * 33;
#pragma unroll
    for (int d = 0; d < D; ++d) p[d] = nom[d];
    p[D] = den;
}

// ---------------------------------------------------------------------------
// Kernel 2: reduce partials over S and divide.
//   One thread per (n, d) output element; t = n*32 + d matches out layout.
// ---------------------------------------------------------------------------
__global__ __launch_bounds__(256) void msk_reduce(const float* __restrict__ part,
                                                  float* __restrict__ out,
                                                  int N, int S) {
    const int t = blockIdx.x * blockDim.x + threadIdx.x;
    const int n = t >> 5;
    const int d = t & 31;
    if (n >= N) return;
    float nom = 0.f, den = 0.f;
    for (int s = 0; s < S; ++s) {
        const float* p = part + ((size_t)s * N + n) * 33;
        nom += p[d];
        den += p[D];
    }
    out[t] = nom / den;
}

// ---------------------------------------------------------------------------
extern "C" void kernel_launch(void* const* d_in, const int* in_sizes, int n_in,
                              void* d_out, int out_size, void* d_ws, size_t ws_size,
                              hipStream_t stream) {
    const float* pts = (const float*)d_in[0];
    const float* ref = (const float*)d_in[1];
    float* out       = (float*)d_out;

    const int N = in_sizes[0] / D;   // 8192
    const int M = in_sizes[1] / D;   // 8192

    // Workspace layout: [ y2 : M floats (256B aligned) ][ partials : S*N*33 floats ]
    size_t y2_bytes = (((size_t)M * sizeof(float)) + 255) & ~(size_t)255;
    float* y2   = (float*)d_ws;
    float* part = (float*)((char*)d_ws + y2_bytes);

    const size_t per_s = (size_t)N * 33 * sizeof(float);
    int S = 16;
    while (S > 1 && y2_bytes + (size_t)S * per_s > ws_size) S >>= 1;
    const int chunk = M / S;

    msk_y2<<<dim3((M + 255) / 256), dim3(256), 0, stream>>>(ref, y2, M);

    dim3 grid1(N / 256, S);
    msk_partial<<<grid1, dim3(256), 0, stream>>>(pts, ref, y2, part, N, chunk);

    msk_reduce<<<dim3((N * D) / 256), dim3(256), 0, stream>>>(part, out, N, S);
}

// Round 2
// 118.421 us; speedup vs baseline: 2.2460x; 2.2460x over previous
//
#include <hip/hip_runtime.h>
#include <hip/hip_bf16.h>

#define D 32
#define FACTOR (-1.0f / 128.0f)   // -1/(2*8^2)
#define LOG2E  1.44269504088896340736f

typedef __attribute__((ext_vector_type(8)))  short bf16x8;
typedef __attribute__((ext_vector_type(16))) float f32x16;
typedef __attribute__((ext_vector_type(4)))  float f32x4;

#if __has_builtin(__builtin_amdgcn_exp2f)
#define EXP2(x) __builtin_amdgcn_exp2f(x)
#else
#define EXP2(x) exp2f(x)
#endif

__device__ __forceinline__ ushort bfr(float x) {
    __hip_bfloat16 h = __float2bfloat16(x);     // RNE
    return *reinterpret_cast<ushort*>(&h);
}
__device__ __forceinline__ float bf2f(ushort u) {
    uint w = ((uint)u) << 16;
    return *reinterpret_cast<float*>(&w);
}
__device__ __forceinline__ uint pk2(float a, float b) {
    return (uint)bfr(a) | ((uint)bfr(b) << 16);
}

// ---------------------------------------------------------------------------
// Prep: bf16 copies of X and Y, transposed yT[d][m], and x2/y2 from the
// ROUNDED values (so s = ||x~ - y~||^2 exactly, modulo fp32 accumulation).
// ---------------------------------------------------------------------------
__global__ __launch_bounds__(256) void msk_prep(const float* __restrict__ X,
                                                const float* __restrict__ Y,
                                                ushort* __restrict__ Xb,
                                                ushort* __restrict__ Yb,
                                                ushort* __restrict__ yT,
                                                float* __restrict__ x2,
                                                float* __restrict__ y2,
                                                int N, int M) {
    const int i = blockIdx.x * 256 + threadIdx.x;
    if (i < N) {
        float s = 0.f; uint w[16];
#pragma unroll
        for (int d = 0; d < D; d += 2) {
            float a = X[(size_t)i * D + d], b = X[(size_t)i * D + d + 1];
            ushort ua = bfr(a), ub = bfr(b);
            w[d >> 1] = (uint)ua | ((uint)ub << 16);
            float fa = bf2f(ua), fb = bf2f(ub);
            s = fmaf(fa, fa, fmaf(fb, fb, s));
        }
        uint4* dst = reinterpret_cast<uint4*>(Xb + (size_t)i * D);
        const uint4* srcw = reinterpret_cast<const uint4*>(w);
#pragma unroll
        for (int q = 0; q < 4; ++q) dst[q] = srcw[q];
        x2[i] = s;
    }
    const int j = i - N;
    if (j >= 0 && j < M) {
        float s = 0.f; uint w[16];
#pragma unroll
        for (int d = 0; d < D; d += 2) {
            float a = Y[(size_t)j * D + d], b = Y[(size_t)j * D + d + 1];
            ushort ua = bfr(a), ub = bfr(b);
            w[d >> 1] = (uint)ua | ((uint)ub << 16);
            float fa = bf2f(ua), fb = bf2f(ub);
            s = fmaf(fa, fa, fmaf(fb, fb, s));
        }
        uint4* dst = reinterpret_cast<uint4*>(Yb + (size_t)j * D);
        const uint4* srcw = reinterpret_cast<const uint4*>(w);
#pragma unroll
        for (int q = 0; q < 4; ++q) dst[q] = srcw[q];
        y2[j] = s;
#pragma unroll
        for (int d = 0; d < D; ++d)
            yT[(size_t)d * M + j] = (ushort)(w[d >> 1] >> ((d & 1) * 16));
    }
}

// ---------------------------------------------------------------------------
// Main fused kernel: per wave a 32-point n-tile, m-chunk of `chunk`.
//   GEMM1 (swapped): S^T[m][n] = dot(y_m, x_n) via 2x mfma_32x32x16 (K=32=D)
//   exp in log2 domain; GEMM2: nom[n][d] += K[n][m] @ y[m][d], K=16 per ks.
//   A-frag of GEMM2 = packed bf16 of S^T regs (no cross-lane moves); the
//   per-lane m-order (16ks + 8*(j>>2) + 4h + (j&3)) is absorbed into the
//   yT B-operand addressing (A/B operand layouts are symmetric).
// ---------------------------------------------------------------------------
__global__ __launch_bounds__(256) void msk_main(const ushort* __restrict__ Xb,
                                                const ushort* __restrict__ Yb,
                                                const ushort* __restrict__ yT,
                                                const float* __restrict__ x2,
                                                const float* __restrict__ y2,
                                                float* __restrict__ part,
                                                int N, int M, int chunk) {
    const int lane = threadIdx.x & 63;
    const int wid  = threadIdx.x >> 6;
    const int h    = lane >> 5;          // half (lane>=32)
    const int ln   = lane & 31;
    const int n0   = blockIdx.x * 128 + wid * 32;
    const int m0b  = blockIdx.y * chunk;

    // x B-fragments (fixed per wave): element (h,j) <-> d = 16*ks + 8h + j
    const ushort* xrow = Xb + (size_t)(n0 + ln) * D + h * 8;
    const bf16x8 xf0 = *reinterpret_cast<const bf16x8*>(xrow);
    const bf16x8 xf1 = *reinterpret_cast<const bf16x8*>(xrow + 16);

    const float F2  = FACTOR * LOG2E;
    const float C2  = -2.0f * F2;
    const float xb2 = x2[n0 + ln] * F2;

    f32x16 nom = {};
    float den = 0.f;

    for (int m0 = m0b; m0 < m0b + chunk; m0 += 32) {
        // GEMM1 A-frags: y rows, same element->d map as x frags
        const ushort* yrow = Yb + (size_t)(m0 + ln) * D + h * 8;
        bf16x8 yf0 = *reinterpret_cast<const bf16x8*>(yrow);
        bf16x8 yf1 = *reinterpret_cast<const bf16x8*>(yrow + 16);
        f32x16 s = {};
        s = __builtin_amdgcn_mfma_f32_32x32x16_bf16(yf0, xf0, s, 0, 0, 0);
        s = __builtin_amdgcn_mfma_f32_32x32x16_bf16(yf1, xf1, s, 0, 0, 0);
        // s reg r: m = m0 + (r&3) + 8*(r>>2) + 4h ; n = n0 + ln

        uint pw[8];
#pragma unroll
        for (int r4 = 0; r4 < 4; ++r4) {
            f32x4 yv = *reinterpret_cast<const f32x4*>(y2 + m0 + r4 * 8 + h * 4);
            float kq[4];
#pragma unroll
            for (int q = 0; q < 4; ++q) {
                float base = fmaf(yv[q], F2, xb2);           // (x2+y2)*F2
                kq[q] = EXP2(fmaf(s[r4 * 4 + q], C2, base)); // exp(FACTOR*(x2+y2-2dot))
            }
            den += (kq[0] + kq[1]) + (kq[2] + kq[3]);
            pw[r4 * 2 + 0] = pk2(kq[0], kq[1]);
            pw[r4 * 2 + 1] = pk2(kq[2], kq[3]);
        }
        union Fu { uint u[4]; bf16x8 v; };
        Fu pa0, pa1;
        pa0.u[0] = pw[0]; pa0.u[1] = pw[1]; pa0.u[2] = pw[2]; pa0.u[3] = pw[3];
        pa1.u[0] = pw[4]; pa1.u[1] = pw[5]; pa1.u[2] = pw[6]; pa1.u[3] = pw[7];

        // GEMM2 B-frags from yT[d][m]: element (h,j) <-> m = 16ks + 8*(j>>2) + 4h + (j&3)
        const ushort* ytr = yT + (size_t)ln * M + m0 + h * 4;
        Fu b0, b1;
        *reinterpret_cast<uint2*>(&b0.u[0]) = *reinterpret_cast<const uint2*>(ytr);
        *reinterpret_cast<uint2*>(&b0.u[2]) = *reinterpret_cast<const uint2*>(ytr + 8);
        *reinterpret_cast<uint2*>(&b1.u[0]) = *reinterpret_cast<const uint2*>(ytr + 16);
        *reinterpret_cast<uint2*>(&b1.u[2]) = *reinterpret_cast<const uint2*>(ytr + 24);

        nom = __builtin_amdgcn_mfma_f32_32x32x16_bf16(pa0.v, b0.v, nom, 0, 0, 0);
        nom = __builtin_amdgcn_mfma_f32_32x32x16_bf16(pa1.v, b1.v, nom, 0, 0, 0);
    }

    // den: halves hold disjoint m partials for the same n=ln
    den += __shfl_xor(den, 32);

    const size_t base = (size_t)blockIdx.y * N;
#pragma unroll
    for (int r = 0; r < 16; ++r) {
        int row = (r & 3) + 8 * (r >> 2) + 4 * h;        // n offset
        part[(base + n0 + row) * 33 + ln] = nom[r];      // d = ln
    }
    if (h == 0) part[(base + n0 + ln) * 33 + 32] = den;
}

// ---------------------------------------------------------------------------
// Reduce over m-chunks and divide.
// ---------------------------------------------------------------------------
__global__ __launch_bounds__(256) void msk_reduce(const float* __restrict__ part,
                                                  float* __restrict__ out,
                                                  int N, int S) {
    const int t = blockIdx.x * blockDim.x + threadIdx.x;
    const int n = t >> 5;
    const int d = t & 31;
    if (n >= N) return;
    float nom = 0.f, den = 0.f;
    for (int s = 0; s < S; ++s) {
        const float* p = part + ((size_t)s * N + n) * 33;
        nom += p[d];
        den += p[D];
    }
    out[t] = nom / den;
}

// ---------------------------------------------------------------------------
extern "C" void kernel_launch(void* const* d_in, const int* in_sizes, int n_in,
                              void* d_out, int out_size, void* d_ws, size_t ws_size,
                              hipStream_t stream) {
    const float* X = (const float*)d_in[0];
    const float* Y = (const float*)d_in[1];
    float* out     = (float*)d_out;

    const int N = in_sizes[0] / D;   // 8192
    const int M = in_sizes[1] / D;   // 8192

    char* p = (char*)d_ws;
    ushort* Xb = (ushort*)p; p += (size_t)N * D * sizeof(ushort);
    ushort* Yb = (ushort*)p; p += (size_t)M * D * sizeof(ushort);
    ushort* yT = (ushort*)p; p += (size_t)M * D * sizeof(ushort);
    float*  x2 = (float*)p;  p += (size_t)N * sizeof(float);
    float*  y2 = (float*)p;  p += (size_t)M * sizeof(float);
    size_t used = (size_t)(p - (char*)d_ws);
    used = (used + 255) & ~(size_t)255;
    float* part = (float*)((char*)d_ws + used);

    const size_t per_s = (size_t)N * 33 * sizeof(float);
    int S = 16;
    while (S > 1 && used + (size_t)S * per_s > ws_size) S >>= 1;
    const int chunk = M / S;

    msk_prep<<<dim3((N + M + 255) / 256), dim3(256), 0, stream>>>(
        X, Y, Xb, Yb, yT, x2, y2, N, M);

    msk_main<<<dim3(N / 128, S), dim3(256), 0, stream>>>(
        Xb, Yb, yT, x2, y2, part, N, M, chunk);

    msk_reduce<<<dim3((N * D) / 256), dim3(256), 0, stream>>>(part, out, N, S);
}